// Round 1
// 296.295 us; speedup vs baseline: 1.2192x; 1.2192x over previous
//
#include <hip/hip_runtime.h>
#include <hip/hip_bf16.h>

// DeepSeek V4 MLA sparse attention, MI355X gfx950.
// Wave-specialized producer/consumer pipeline:
//   waves 0-3  (S-waves):  QK^T + in-register online softmax -> P, alpha
//   waves 4-11 (PV-waves): stage iter k+1 (gather) + PV MFMA for iter k-1
// One barrier per tick (33 ticks), double-buffered LDS.
#define T_TOK 512
#define NH    64
#define HD    576
#define DVAL  512
#define NKV   8192
#define TOPK  1024
#define KT    32
#define NITER (TOPK / KT)   // 32
#define KSTEPS (HD / 32)    // 18
#define SCALE 0.041666666666666664f  // 1/24

typedef __attribute__((ext_vector_type(4))) float f32x4;
typedef __attribute__((ext_vector_type(8))) _Float16 half8;
typedef __attribute__((ext_vector_type(4))) unsigned short us4;
typedef __attribute__((ext_vector_type(8))) unsigned short us8;
typedef __attribute__((ext_vector_type(4))) int i32x4;

__device__ __forceinline__ unsigned short f2h(float x) {
    _Float16 h = (_Float16)x;
    return __builtin_bit_cast(unsigned short, h);
}

// ---- prep: kv fp32 -> fp16 in workspace (9.4 MB) ----
__global__ void cvt_kv_f16(const float* __restrict__ kv, unsigned short* __restrict__ kvb) {
    int i = blockIdx.x * 256 + threadIdx.x;          // 0 .. 589823 (NKV*HD/8 exactly)
    const f32x4* src = (const f32x4*)kv + (size_t)i * 2;
    f32x4 a = src[0];
    f32x4 b = src[1];
    us8 w;
    w[0]=f2h(a[0]); w[1]=f2h(a[1]); w[2]=f2h(a[2]); w[3]=f2h(a[3]);
    w[4]=f2h(b[0]); w[5]=f2h(b[1]); w[6]=f2h(b[2]); w[7]=f2h(b[3]);
    ((us8*)kvb)[i] = w;
}

#define G_LD  584   // 576 + 8 fp16 pad; row = 1168 B (16B-mult, 73 granules/row: odd -> S-reads spread)
#define P_LD  40    // 32 + 8 pad
// gt: flat [512 rows][32 keys] fp16, XOR-swizzled at 16B-granule level.
// idx bits 3-5 ^= (row>>2)&7 : bijective within each 128-elem block; makes the
// transposed stage-write (lane -> rows 4l..4l+3) hit all 8 bank-quads (was 32-way).
#define GT_IDX(row,key) (((((row) << 5) | (key))) ^ ((((row) >> 2) & 7) << 3))

__device__ __forceinline__ void stage_load(
    const unsigned short* __restrict__ kvb, const int* __restrict__ tkrow,
    int it, int w8, int lm, int kg, us4* v, us4* vrope)
{
    const int* ip = tkrow + it * KT + kg * 8;
    i32x4 ra = *(const i32x4*)ip;
    i32x4 rb = *(const i32x4*)(ip + 4);
    int rows[8];
    rows[0]=ra[0]; rows[1]=ra[1]; rows[2]=ra[2]; rows[3]=ra[3];
    rows[4]=rb[0]; rows[5]=rb[1]; rows[6]=rb[2]; rows[7]=rb[3];
    int d0 = w8 * 64 + lm * 4;
    #pragma unroll
    for (int j = 0; j < 8; j++) {
        int r = rows[j] < 0 ? 0 : rows[j];
        v[j] = *(const us4*)(kvb + (size_t)r * HD + d0);
    }
    int kr = tkrow[it * KT + w8 * 4 + kg];
    if (kr < 0) kr = 0;
    *vrope = *(const us4*)(kvb + (size_t)kr * HD + 512 + lm * 4);
}

__device__ __forceinline__ void stage_write(
    int w8, int lm, int kg, const us4* v, us4 vrope,
    unsigned short (*gp)[G_LD], unsigned short* gtp)
{
    int d0 = w8 * 64 + lm * 4;
    #pragma unroll
    for (int j = 0; j < 8; j++)
        *(us4*)&gp[kg * 8 + j][d0] = v[j];
    #pragma unroll
    for (int dd = 0; dd < 4; dd++) {
        us8 wv;
        wv[0]=v[0][dd]; wv[1]=v[1][dd]; wv[2]=v[2][dd]; wv[3]=v[3][dd];
        wv[4]=v[4][dd]; wv[5]=v[5][dd]; wv[6]=v[6][dd]; wv[7]=v[7][dd];
        *(us8*)&gtp[GT_IDX(d0 + dd, kg * 8)] = wv;
    }
    *(us4*)&gp[w8 * 4 + kg][512 + lm * 4] = vrope;   // rope dims, g only
}

__global__ __launch_bounds__(768, 3) void mla_sparse_kernel(
    const float* __restrict__ q, const int* __restrict__ topk,
    const float* __restrict__ sink, const unsigned short* __restrict__ kvb,
    float* __restrict__ out)
{
    __shared__ unsigned short g2[2][KT][G_LD];     // 74,752 B  (S-GEMM operand, [key][d])
    __shared__ unsigned short gtb[2][DVAL * 32];   // 65,536 B  (PV operand, swizzled [vcol][key])
    __shared__ unsigned short pbuf[2][NH][P_LD];   // 10,240 B  (softmaxed P, fp16)
    __shared__ float arun[2][NH];                  //    512 B  (per-iter alpha)
    __shared__ float lrunL[NH];                    //    256 B  (final denom)
    // total 151,296 B -> 1 block/CU, 12 waves

    const int t    = blockIdx.x;
    const int tid  = threadIdx.x;
    const int lane = tid & 63;
    const int quad = lane >> 4;
    const int l16  = lane & 15;
    const int wave = __builtin_amdgcn_readfirstlane(tid >> 6);  // force scalar branch
    const int* tkrow = topk + (size_t)t * TOPK;

    if (wave < 4) {
        // ================= S / softmax waves: wave w owns heads w*16 .. +15 =================
        const int w = wave;
        half8 qf[KSTEPS];   // 72 VGPRs (this path never holds acc)
        {
            const float* qrow = q + ((size_t)t * NH + (w * 16 + l16)) * HD;
            #pragma unroll
            for (int ks = 0; ks < KSTEPS; ks++) {
                int d0 = ks * 32 + quad * 8;
                f32x4 a = *(const f32x4*)(qrow + d0);
                f32x4 b = *(const f32x4*)(qrow + d0 + 4);
                half8 h;
                h[0]=(_Float16)a[0]; h[1]=(_Float16)a[1]; h[2]=(_Float16)a[2]; h[3]=(_Float16)a[3];
                h[4]=(_Float16)b[0]; h[5]=(_Float16)b[1]; h[6]=(_Float16)b[2]; h[7]=(_Float16)b[3];
                qf[ks] = h;
            }
        }
        // sink folded into online-softmax init: m = sink[h], l = exp(sink-m) = 1
        f32x4 sk = *(const f32x4*)(sink + w * 16 + quad * 4);
        float m_run[4], l_run[4];
        #pragma unroll
        for (int r = 0; r < 4; r++) { m_run[r] = sk[r]; l_run[r] = 1.0f; }

        __syncthreads();                                   // B0: iter-0 staging done

        for (int k = 0; k <= NITER; k++) {
            if (k < NITER) {
                const int par = k & 1;
                // S = Q * G^T, full 32-key row per wave (2 ntiles)
                f32x4 s0 = {0.f,0.f,0.f,0.f}, s1 = {0.f,0.f,0.f,0.f};
                #pragma unroll
                for (int ks = 0; ks < KSTEPS; ks++) {
                    half8 b0 = *(const half8*)&g2[par][l16][ks * 32 + quad * 8];
                    half8 b1 = *(const half8*)&g2[par][16 + l16][ks * 32 + quad * 8];
                    s0 = __builtin_amdgcn_mfma_f32_16x16x32_f16(qf[ks], b0, s0, 0, 0, 0);
                    s1 = __builtin_amdgcn_mfma_f32_16x16x32_f16(qf[ks], b1, s1, 0, 0, 0);
                }
                // bias from topk sign, computed in-lane (L1-resident)
                int i0 = tkrow[k * KT + l16];
                int i1 = tkrow[k * KT + 16 + l16];
                float bb0 = i0 < 0 ? -__builtin_inff() : 0.0f;
                float bb1 = i1 < 0 ? -__builtin_inff() : 0.0f;
                // in-register online softmax over 32 keys (butterfly over 16 lanes)
                float v0[4], v1[4], tmx[4];
                #pragma unroll
                for (int r = 0; r < 4; r++) {
                    v0[r] = s0[r] * SCALE + bb0;
                    v1[r] = s1[r] * SCALE + bb1;
                    tmx[r] = fmaxf(v0[r], v1[r]);
                }
                #pragma unroll
                for (int m = 1; m < 16; m <<= 1) {
                    #pragma unroll
                    for (int r = 0; r < 4; r++)
                        tmx[r] = fmaxf(tmx[r], __shfl_xor(tmx[r], m));
                }
                float p0[4], p1[4], ps[4], al[4];
                #pragma unroll
                for (int r = 0; r < 4; r++) {
                    float mn = fmaxf(m_run[r], tmx[r]);    // m_run >= sink: always finite
                    al[r] = __expf(m_run[r] - mn);
                    p0[r] = __expf(v0[r] - mn);            // -inf input -> 0, safe
                    p1[r] = __expf(v1[r] - mn);
                    ps[r] = p0[r] + p1[r];
                    m_run[r] = mn;
                }
                #pragma unroll
                for (int m = 1; m < 16; m <<= 1) {
                    #pragma unroll
                    for (int r = 0; r < 4; r++)
                        ps[r] += __shfl_xor(ps[r], m);
                }
                #pragma unroll
                for (int r = 0; r < 4; r++)
                    l_run[r] = l_run[r] * al[r] + ps[r];
                const int hb = w * 16 + quad * 4;
                if (l16 == 0) {
                    f32x4 a4; a4[0]=al[0]; a4[1]=al[1]; a4[2]=al[2]; a4[3]=al[3];
                    *(f32x4*)&arun[par][hb] = a4;
                }
                #pragma unroll
                for (int r = 0; r < 4; r++) {
                    pbuf[par][hb + r][l16]      = f2h(p0[r]);
                    pbuf[par][hb + r][16 + l16] = f2h(p1[r]);
                }
            }
            __syncthreads();                               // tick barrier
        }
        if (l16 == 0) {
            f32x4 l4; l4[0]=l_run[0]; l4[1]=l_run[1]; l4[2]=l_run[2]; l4[3]=l_run[3];
            *(f32x4*)&lrunL[w * 16 + quad * 4] = l4;
        }
        __syncthreads();                                   // B_final
    } else {
        // ================= PV / staging waves: wave owns O[:, (wave-4)*64 .. +63] =================
        const int w8   = wave - 4;          // 0..7
        const int col0 = w8 * 64;
        const int kg   = quad;              // 8-key group for staging
        const int lm   = l16;               // 4-dim group within wave's 64-dim slice
        f32x4 acc[4][4];
        f32x4 zero = {0.f,0.f,0.f,0.f};
        #pragma unroll
        for (int mt = 0; mt < 4; mt++)
            #pragma unroll
            for (int nt = 0; nt < 4; nt++) acc[mt][nt] = zero;

        {   // prologue: stage iter 0 (parity 0)
            us4 v[8]; us4 vrope;
            stage_load(kvb, tkrow, 0, w8, lm, kg, v, &vrope);
            stage_write(w8, lm, kg, v, vrope, g2[0], gtb[0]);
        }
        __syncthreads();                                   // B0

        for (int k = 0; k <= NITER; k++) {
            if (k == 0) {
                us4 v[8]; us4 vrope;
                stage_load(kvb, tkrow, 1, w8, lm, kg, v, &vrope);
                stage_write(w8, lm, kg, v, vrope, g2[1], gtb[1]);
            } else {
                const int par = (k - 1) & 1;
                // frag reads for iter k-1 (MUST complete before same-parity stage writes below)
                half8 pa[4], vb[4];
                #pragma unroll
                for (int mt = 0; mt < 4; mt++)
                    pa[mt] = *(const half8*)&pbuf[par][mt * 16 + l16][quad * 8];
                #pragma unroll
                for (int nt = 0; nt < 4; nt++)
                    vb[nt] = *(const half8*)&gtb[par][GT_IDX(col0 + nt * 16 + l16, quad * 8)];
                asm volatile("s_waitcnt lgkmcnt(0)" ::: "memory");  // WAR fence: reads landed

                const bool do_stage = (k + 1) < NITER;
                us4 v[8]; us4 vrope;
                if (do_stage)
                    stage_load(kvb, tkrow, k + 1, w8, lm, kg, v, &vrope);  // issue early

                // rescale by alpha, accumulate P * Gv  (gather latency hides under this)
                #pragma unroll
                for (int mt = 0; mt < 4; mt++) {
                    f32x4 av = *(const f32x4*)&arun[par][mt * 16 + quad * 4];
                    #pragma unroll
                    for (int nt = 0; nt < 4; nt++) {
                        acc[mt][nt] *= av;
                        acc[mt][nt] = __builtin_amdgcn_mfma_f32_16x16x32_f16(pa[mt], vb[nt], acc[mt][nt], 0, 0, 0);
                    }
                }
                if (do_stage) {
                    const int spar = (k + 1) & 1;
                    stage_write(w8, lm, kg, v, vrope, g2[spar], gtb[spar]); // write late
                }
            }
            __syncthreads();                               // tick barrier
        }
        __syncthreads();                                   // B_final (lrunL ready)

        // epilogue: divide by denom, store
        #pragma unroll
        for (int mt = 0; mt < 4; mt++) {
            f32x4 lv = *(const f32x4*)&lrunL[mt * 16 + quad * 4];
            f32x4 li;
            li[0] = 1.0f / lv[0]; li[1] = 1.0f / lv[1];
            li[2] = 1.0f / lv[2]; li[3] = 1.0f / lv[3];
            #pragma unroll
            for (int nt = 0; nt < 4; nt++) {
                int vcol = col0 + nt * 16 + l16;
                f32x4 r = acc[mt][nt] * li;
                #pragma unroll
                for (int rr = 0; rr < 4; rr++) {
                    int head = mt * 16 + quad * 4 + rr;
                    out[((size_t)t * NH + head) * DVAL + vcol] = r[rr];
                }
            }
        }
    }
}

extern "C" void kernel_launch(void* const* d_in, const int* in_sizes, int n_in,
                              void* d_out, int out_size, void* d_ws, size_t ws_size,
                              hipStream_t stream) {
    const float* q    = (const float*)d_in[0];   // [512,64,576]
    const float* kv   = (const float*)d_in[1];   // [8192,576]
    const int*   topk = (const int*)d_in[2];     // [512,1024]
    const float* sink = (const float*)d_in[3];   // [64]
    float* out = (float*)d_out;                  // [512,64,512]
    unsigned short* kvb = (unsigned short*)d_ws; // fp16 kv cache, 9,437,184 B

    cvt_kv_f16<<<NKV * HD / (256 * 8), 256, 0, stream>>>(kv, kvb);
    mla_sparse_kernel<<<T_TOK, 768, 0, stream>>>(q, topk, sink, kvb, out);
}

// Round 2
// 272.160 us; speedup vs baseline: 1.3273x; 1.0887x over previous
//
#include <hip/hip_runtime.h>
#include <hip/hip_bf16.h>

// DeepSeek V4 MLA sparse attention, MI355X gfx950.
// Wave-specialized producer/consumer pipeline, depth-2 gather prefetch:
//   waves 0-3  (S-waves):  QK^T + in-register online softmax (DPP butterflies)
//   waves 4-11 (PV-waves): issue gather(k+2) early, PV MFMA(k-1), LDS-write tile(k+1)
#define T_TOK 512
#define NH    64
#define HD    576
#define DVAL  512
#define NKV   8192
#define TOPK  1024
#define KT    32
#define NITER (TOPK / KT)   // 32
#define KSTEPS (HD / 32)    // 18
#define SCALE 0.041666666666666664f  // 1/24
#define LOG2E 1.4426950408889634f
#define QSCL  (SCALE * LOG2E)

typedef __attribute__((ext_vector_type(4))) float f32x4;
typedef __attribute__((ext_vector_type(8))) _Float16 half8;
typedef __attribute__((ext_vector_type(4))) unsigned short us4;
typedef __attribute__((ext_vector_type(8))) unsigned short us8;
typedef __attribute__((ext_vector_type(4))) int i32x4;

__device__ __forceinline__ unsigned short f2h(float x) {
    _Float16 h = (_Float16)x;
    return __builtin_bit_cast(unsigned short, h);
}

__device__ __forceinline__ float fexp2(float x) {
#if __has_builtin(__builtin_amdgcn_exp2f)
    return __builtin_amdgcn_exp2f(x);
#else
    return __expf(x * 0.6931471805599453f);
#endif
}

// DPP 16-lane butterfly reductions (VALU-only, no LDS crossbar)
template<int CTRL>
__device__ __forceinline__ float dppmv(float x) {
    int r = __builtin_amdgcn_update_dpp(0, __builtin_bit_cast(int, x), CTRL, 0xF, 0xF, true);
    return __builtin_bit_cast(float, r);
}
__device__ __forceinline__ float red16max(float x) {
    x = fmaxf(x, dppmv<0xB1>(x));    // quad_perm [1,0,3,2]  (xor1)
    x = fmaxf(x, dppmv<0x4E>(x));    // quad_perm [2,3,0,1]  (xor2)
    x = fmaxf(x, dppmv<0x141>(x));   // row_half_mirror
    x = fmaxf(x, dppmv<0x140>(x));   // row_mirror
    return x;
}
__device__ __forceinline__ float red16sum(float x) {
    x += dppmv<0xB1>(x);
    x += dppmv<0x4E>(x);
    x += dppmv<0x141>(x);
    x += dppmv<0x140>(x);
    return x;
}

// tick barrier: producer-side lgkmcnt drain only; global loads stay in flight
#define TICK_BARRIER() do {                                   \
    asm volatile("s_waitcnt lgkmcnt(0)" ::: "memory");        \
    __builtin_amdgcn_s_barrier();                             \
    asm volatile("" ::: "memory");                            \
} while (0)

// ---- prep: kv fp32 -> fp16 in workspace (9.4 MB) ----
__global__ void cvt_kv_f16(const float* __restrict__ kv, unsigned short* __restrict__ kvb) {
    int i = blockIdx.x * 256 + threadIdx.x;
    const f32x4* src = (const f32x4*)kv + (size_t)i * 2;
    f32x4 a = src[0];
    f32x4 b = src[1];
    us8 w;
    w[0]=f2h(a[0]); w[1]=f2h(a[1]); w[2]=f2h(a[2]); w[3]=f2h(a[3]);
    w[4]=f2h(b[0]); w[5]=f2h(b[1]); w[6]=f2h(b[2]); w[7]=f2h(b[3]);
    ((us8*)kvb)[i] = w;
}

#define G_LD  584   // 576+8 pad; row = 292 words (== 4 mod 32: S-reads conflict-free)
#define P_LD  40
// gt: flat [512 rows][32 keys] fp16, 16B-granule XOR swizzle (bijective)
#define GT_IDX(row,key) (((((row) << 5) | (key))) ^ ((((row) >> 2) & 7) << 3))

struct StageRegs { us8 v[4]; us4 rope; };

// lane decomposition for staging: kg = lane>>3 (key group of 4), lm = lane&7 (8-dim group)
__device__ __forceinline__ void stage_load(
    const unsigned short* __restrict__ kvb, const int* __restrict__ tkrow,
    int it, int w8, int kg, int lm, int quad, int l16, StageRegs& R)
{
    const int* ip = tkrow + it * KT + kg * 4;
    i32x4 r4 = *(const i32x4*)ip;
    int d0 = w8 * 64 + lm * 8;
    #pragma unroll
    for (int j = 0; j < 4; j++) {
        int r = r4[j] < 0 ? 0 : r4[j];
        R.v[j] = *(const us8*)(kvb + (size_t)r * HD + d0);
    }
    int kr = tkrow[it * KT + w8 * 4 + quad];
    if (kr < 0) kr = 0;
    R.rope = *(const us4*)(kvb + (size_t)kr * HD + 512 + l16 * 4);
}

__device__ __forceinline__ void stage_write(
    int w8, int kg, int lm, int quad, int l16, const StageRegs& R,
    unsigned short (*gp)[G_LD], unsigned short* gtp)
{
    int d0 = w8 * 64 + lm * 8;
    #pragma unroll
    for (int j = 0; j < 4; j++)
        *(us8*)&gp[kg * 4 + j][d0] = R.v[j];
    #pragma unroll
    for (int e = 0; e < 8; e++) {
        us4 wv;
        wv[0] = R.v[0][e]; wv[1] = R.v[1][e]; wv[2] = R.v[2][e]; wv[3] = R.v[3][e];
        *(us4*)&gtp[GT_IDX(d0 + e, kg * 4)] = wv;
    }
    *(us4*)&gp[w8 * 4 + quad][512 + l16 * 4] = R.rope;   // rope dims, g only
}

// one PV tick: issue load(tau+2), alpha-rescale + MFMA(tau-1), write tile(tau+1)
__device__ __forceinline__ void pv_tick(
    int tau, const unsigned short* __restrict__ kvb, const int* __restrict__ tkrow,
    int w8, int kg, int lm, int quad, int l16, int col0,
    StageRegs& Lset, StageRegs& Wset,
    unsigned short (*g2p)[G_LD], unsigned short* gtp,
    unsigned short (*pb)[P_LD], const float* ar,
    f32x4 (&acc)[4][4])
{
    if (tau + 2 < NITER)
        stage_load(kvb, tkrow, tau + 2, w8, kg, lm, quad, l16, Lset);  // issue early

    // alpha rescale (skip when all alphas are exactly 1 — defer-max)
    f32x4 avv[4];
    bool one = true;
    #pragma unroll
    for (int mt = 0; mt < 4; mt++) {
        avv[mt] = *(const f32x4*)&ar[mt * 16 + quad * 4];
        one = one && (avv[mt][0] == 1.f) && (avv[mt][1] == 1.f)
                  && (avv[mt][2] == 1.f) && (avv[mt][3] == 1.f);
    }
    if (!__all((int)one)) {
        #pragma unroll
        for (int mt = 0; mt < 4; mt++)
            #pragma unroll
            for (int nt = 0; nt < 4; nt++) acc[mt][nt] *= avv[mt];
    }

    half8 pa[4];
    #pragma unroll
    for (int mt = 0; mt < 4; mt++)
        pa[mt] = *(const half8*)&pb[mt * 16 + l16][quad * 8];

    __builtin_amdgcn_s_setprio(1);
    #pragma unroll
    for (int nt = 0; nt < 4; nt++) {
        half8 vb = *(const half8*)&gtp[GT_IDX(col0 + nt * 16 + l16, quad * 8)];
        #pragma unroll
        for (int mt = 0; mt < 4; mt++)
            acc[mt][nt] = __builtin_amdgcn_mfma_f32_16x16x32_f16(pa[mt], vb, acc[mt][nt], 0, 0, 0);
    }
    __builtin_amdgcn_s_setprio(0);

    asm volatile("s_waitcnt lgkmcnt(0)" ::: "memory");   // WAR fence: frag reads landed
    if (tau + 1 < NITER)
        stage_write(w8, kg, lm, quad, l16, Wset, g2p, gtp);
}

__global__ __launch_bounds__(768, 3) void mla_sparse_kernel(
    const float* __restrict__ q, const int* __restrict__ topk,
    const float* __restrict__ sink, const unsigned short* __restrict__ kvb,
    float* __restrict__ out)
{
    __shared__ unsigned short g2[2][KT][G_LD];     // 74,752 B  (S operand, [key][d])
    __shared__ unsigned short gtb[2][DVAL * 32];   // 65,536 B  (PV operand, swizzled)
    __shared__ unsigned short pbuf[2][NH][P_LD];   // 10,240 B
    __shared__ float arun[2][NH];                  //    512 B
    __shared__ float lrunL[NH];                    //    256 B
    // total 151,296 B -> 1 block/CU, 12 waves

    const int t    = blockIdx.x;
    const int tid  = threadIdx.x;
    const int lane = tid & 63;
    const int quad = lane >> 4;
    const int l16  = lane & 15;
    const int wave = __builtin_amdgcn_readfirstlane(tid >> 6);
    const int* tkrow = topk + (size_t)t * TOPK;

    if (wave < 4) {
        // ================= S / softmax waves =================
        const int w  = wave;
        const int qo = quad * 8;
        half8 qf[KSTEPS];   // Q pre-scaled by SCALE*log2e
        {
            const float* qrow = q + ((size_t)t * NH + (w * 16 + l16)) * HD;
            #pragma unroll
            for (int ks = 0; ks < KSTEPS; ks++) {
                int d0 = ks * 32 + qo;
                f32x4 a = *(const f32x4*)(qrow + d0);
                f32x4 b = *(const f32x4*)(qrow + d0 + 4);
                half8 h;
                h[0]=(_Float16)(a[0]*QSCL); h[1]=(_Float16)(a[1]*QSCL);
                h[2]=(_Float16)(a[2]*QSCL); h[3]=(_Float16)(a[3]*QSCL);
                h[4]=(_Float16)(b[0]*QSCL); h[5]=(_Float16)(b[1]*QSCL);
                h[6]=(_Float16)(b[2]*QSCL); h[7]=(_Float16)(b[3]*QSCL);
                qf[ks] = h;
            }
        }
        // invalid-key bitmasks, one per key half (removes per-tick topk loads)
        unsigned mb0 = 0, mb1 = 0;
        #pragma unroll 4
        for (int kk = 0; kk < NITER; kk++) {
            mb0 |= (tkrow[kk * KT + l16]      < 0) ? (1u << kk) : 0u;
            mb1 |= (tkrow[kk * KT + 16 + l16] < 0) ? (1u << kk) : 0u;
        }
        // sink folded (log2 domain): m = sink*log2e, l = 1
        f32x4 sk = *(const f32x4*)(sink + w * 16 + quad * 4);
        float m_run[4], l_run[4];
        #pragma unroll
        for (int r = 0; r < 4; r++) { m_run[r] = sk[r] * LOG2E; l_run[r] = 1.0f; }

        __syncthreads();                                   // B0

        for (int k = 0; k <= NITER; k++) {
            if (k < NITER) {
                const int par = k & 1;
                const unsigned short (*gp)[G_LD] = g2[par];
                f32x4 zero = {0.f,0.f,0.f,0.f};
                f32x4 s0a = zero, s0b = zero, s1a = zero, s1b = zero;
                __builtin_amdgcn_s_setprio(1);
                #pragma unroll
                for (int ks = 0; ks < KSTEPS; ks += 2) {
                    half8 b0 = *(const half8*)&gp[l16][ks * 32 + qo];
                    half8 b1 = *(const half8*)&gp[16 + l16][ks * 32 + qo];
                    s0a = __builtin_amdgcn_mfma_f32_16x16x32_f16(qf[ks], b0, s0a, 0, 0, 0);
                    s1a = __builtin_amdgcn_mfma_f32_16x16x32_f16(qf[ks], b1, s1a, 0, 0, 0);
                    half8 c0 = *(const half8*)&gp[l16][ks * 32 + 32 + qo];
                    half8 c1 = *(const half8*)&gp[16 + l16][ks * 32 + 32 + qo];
                    s0b = __builtin_amdgcn_mfma_f32_16x16x32_f16(qf[ks+1], c0, s0b, 0, 0, 0);
                    s1b = __builtin_amdgcn_mfma_f32_16x16x32_f16(qf[ks+1], c1, s1b, 0, 0, 0);
                }
                __builtin_amdgcn_s_setprio(0);
                f32x4 s0 = s0a + s0b, s1 = s1a + s1b;

                const float NEG = -__builtin_inff();
                const bool bad0 = (mb0 >> k) & 1;
                const bool bad1 = (mb1 >> k) & 1;
                float v0[4], v1[4], tmx[4];
                #pragma unroll
                for (int r = 0; r < 4; r++) {
                    v0[r] = bad0 ? NEG : s0[r];
                    v1[r] = bad1 ? NEG : s1[r];
                    tmx[r] = red16max(fmaxf(v0[r], v1[r]));
                }
                float al[4], p0[4], p1[4];
                #pragma unroll
                for (int r = 0; r < 4; r++) {
                    float mn = fmaxf(m_run[r], tmx[r]);
                    al[r] = fexp2(m_run[r] - mn);
                    p0[r] = fexp2(v0[r] - mn);
                    p1[r] = fexp2(v1[r] - mn);
                    m_run[r] = mn;
                    float ps = red16sum(p0[r] + p1[r]);
                    l_run[r] = l_run[r] * al[r] + ps;
                }
                const int hb = w * 16 + quad * 4;
                if (l16 == 0) {
                    f32x4 a4; a4[0]=al[0]; a4[1]=al[1]; a4[2]=al[2]; a4[3]=al[3];
                    *(f32x4*)&arun[par][hb] = a4;
                }
                #pragma unroll
                for (int r = 0; r < 4; r++) {
                    pbuf[par][hb + r][l16]      = f2h(p0[r]);
                    pbuf[par][hb + r][16 + l16] = f2h(p1[r]);
                }
            }
            TICK_BARRIER();
        }
        if (l16 == 0) {
            f32x4 l4; l4[0]=l_run[0]; l4[1]=l_run[1]; l4[2]=l_run[2]; l4[3]=l_run[3];
            *(f32x4*)&lrunL[w * 16 + quad * 4] = l4;
        }
        __syncthreads();                                   // B_final
    } else {
        // ================= PV / staging waves =================
        const int w8   = wave - 4;
        const int col0 = w8 * 64;
        const int kg   = lane >> 3;
        const int lm   = lane & 7;
        f32x4 acc[4][4];
        f32x4 zero = {0.f,0.f,0.f,0.f};
        #pragma unroll
        for (int mt = 0; mt < 4; mt++)
            #pragma unroll
            for (int nt = 0; nt < 4; nt++) acc[mt][nt] = zero;

        StageRegs A, B;
        stage_load(kvb, tkrow, 0, w8, kg, lm, quad, l16, A);
        stage_write(w8, kg, lm, quad, l16, A, g2[0], gtb[0]);
        stage_load(kvb, tkrow, 1, w8, kg, lm, quad, l16, B);
        __syncthreads();                                   // B0

        // tick 0: no MFMA yet — prefetch tile 2, write tile 1
        stage_load(kvb, tkrow, 2, w8, kg, lm, quad, l16, A);
        stage_write(w8, kg, lm, quad, l16, B, g2[1], gtb[1]);
        TICK_BARRIER();

        for (int k = 1; k < NITER; k += 2) {
            // tick k (odd): MFMA(k-1) par0; load(k+2)->B; write(k+1) par0 from A
            pv_tick(k, kvb, tkrow, w8, kg, lm, quad, l16, col0,
                    B, A, g2[0], gtb[0], pbuf[0], arun[0], acc);
            TICK_BARRIER();
            // tick k+1 (even): MFMA(k) par1; load(k+3)->A; write(k+2) par1 from B
            pv_tick(k + 1, kvb, tkrow, w8, kg, lm, quad, l16, col0,
                    A, B, g2[1], gtb[1], pbuf[1], arun[1], acc);
            TICK_BARRIER();
        }
        __syncthreads();                                   // B_final (lrunL ready)

        // epilogue: divide by denom, store
        #pragma unroll
        for (int mt = 0; mt < 4; mt++) {
            f32x4 lv = *(const f32x4*)&lrunL[mt * 16 + quad * 4];
            f32x4 li;
            li[0] = 1.0f / lv[0]; li[1] = 1.0f / lv[1];
            li[2] = 1.0f / lv[2]; li[3] = 1.0f / lv[3];
            #pragma unroll
            for (int nt = 0; nt < 4; nt++) {
                int vcol = col0 + nt * 16 + l16;
                f32x4 r = acc[mt][nt] * li;
                #pragma unroll
                for (int rr = 0; rr < 4; rr++) {
                    int head = mt * 16 + quad * 4 + rr;
                    out[((size_t)t * NH + head) * DVAL + vcol] = r[rr];
                }
            }
        }
    }
}

extern "C" void kernel_launch(void* const* d_in, const int* in_sizes, int n_in,
                              void* d_out, int out_size, void* d_ws, size_t ws_size,
                              hipStream_t stream) {
    const float* q    = (const float*)d_in[0];   // [512,64,576]
    const float* kv   = (const float*)d_in[1];   // [8192,576]
    const int*   topk = (const int*)d_in[2];     // [512,1024]
    const float* sink = (const float*)d_in[3];   // [64]
    float* out = (float*)d_out;                  // [512,64,512]
    unsigned short* kvb = (unsigned short*)d_ws; // fp16 kv cache, 9,437,184 B

    cvt_kv_f16<<<NKV * HD / (256 * 8), 256, 0, stream>>>(kv, kvb);
    mla_sparse_kernel<<<T_TOK, 768, 0, stream>>>(q, topk, sink, kvb, out);
}